// Round 1
// baseline (649.852 us; speedup 1.0000x reference)
//
#include <hip/hip_runtime.h>
#include <hip/hip_bf16.h>
#include <stdint.h>

// Problem dims (fixed)
#define B_DIM 4096
#define DH    2048
#define K_DIM 4096   // D_IN + D_H (concat K)
#define N_DIM 8192   // 4 gates * DH (concat N)

typedef __bf16  bf16x8 __attribute__((ext_vector_type(8)));
typedef float   f32x4  __attribute__((ext_vector_type(4)));

__device__ __forceinline__ unsigned short f2bf(float f) {
  // round-to-nearest-even bf16
  unsigned int u = __float_as_uint(f);
  u += 0x7FFFu + ((u >> 16) & 1u);
  return (unsigned short)(u >> 16);
}

// ---------- kernel 1: cast+concat x,h -> A bf16 [4096][4096] ----------
__global__ void cast_cat_A(const float* __restrict__ x, const float* __restrict__ h,
                           unsigned short* __restrict__ Abuf) {
  int idx = blockIdx.x * 256 + threadIdx.x;        // 0 .. 4,194,303
  const int half = B_DIM * (DH / 4);               // 2,097,152 float4 units per source
  bool isx = (idx < half);
  int i2 = isx ? idx : idx - half;
  int b  = i2 >> 9;                                // row
  int c4 = i2 & 511;                               // float4 col
  const float* src = (isx ? x : h) + (((size_t)b) << 11) + (c4 << 2);
  float4 v = *(const float4*)src;
  ushort4 o;
  o.x = f2bf(v.x); o.y = f2bf(v.y); o.z = f2bf(v.z); o.w = f2bf(v.w);
  int col = (isx ? 0 : DH) + (c4 << 2);
  *(ushort4*)(Abuf + (size_t)b * K_DIM + col) = o;
}

// ---------- kernel 2: transpose+cast weights -> Bt bf16 [8192][4096] ----------
// Bt[n][k]: n = g*2048 + j ; k<2048 -> W_g[k][j], k>=2048 -> U_g[k-2048][j]
__global__ void transpose_cast_B(const float* __restrict__ Wi, const float* __restrict__ Ui,
                                 const float* __restrict__ Wf, const float* __restrict__ Uf,
                                 const float* __restrict__ Wo, const float* __restrict__ Uo,
                                 const float* __restrict__ Wz, const float* __restrict__ Uz,
                                 unsigned short* __restrict__ Bt) {
  __shared__ unsigned short lds[64 * 68];          // pad 68: 8B-aligned rows, broken bank stride
  const int k0 = blockIdx.x * 64;                  // 0..4032
  const int n0 = blockIdx.y * 64;                  // 0..8128 (never straddles a gate: 2048%64==0)
  const int g  = n0 >> 11;
  const int j0 = n0 & 2047;
  const float* W = (g == 0) ? Wi : (g == 1) ? Wf : (g == 2) ? Wo : Wz;
  const float* U = (g == 0) ? Ui : (g == 1) ? Uf : (g == 2) ? Uo : Uz;
  const float* src = ((k0 < DH) ? (W + (size_t)k0 * DH)
                                : (U + (size_t)(k0 - DH) * DH)) + j0;
  const int t = threadIdx.x;
  #pragma unroll
  for (int r = 0; r < 4; ++r) {                    // read [k][j] coalesced along j
    int slot = r * 256 + t;                        // 1024 slots = 64 rows x 16 float4
    int kk = slot >> 4;
    int c4 = slot & 15;
    float4 v = *(const float4*)(src + (size_t)kk * DH + (c4 << 2));
    int n = c4 << 2;
    lds[(n + 0) * 68 + kk] = f2bf(v.x);
    lds[(n + 1) * 68 + kk] = f2bf(v.y);
    lds[(n + 2) * 68 + kk] = f2bf(v.z);
    lds[(n + 3) * 68 + kk] = f2bf(v.w);
  }
  __syncthreads();
  #pragma unroll
  for (int r = 0; r < 4; ++r) {                    // write [n][k] coalesced along k
    int slot = r * 256 + t;
    int nn = slot >> 4;
    int c8 = slot & 15;                            // 16 chunks of 4 shorts = 64 k
    *(ushort4*)(Bt + (size_t)(n0 + nn) * K_DIM + k0 + (c8 << 2)) =
        *(const ushort4*)(lds + nn * 68 + (c8 << 2));
  }
}

// ---------- kernel 3: GEMM C[4096][8192] = A[4096][4096] @ Bt[8192][4096]^T ----------
// m97-ladder structure: 128x128 tile, BK=32, 4 waves, 4x4 16x16x32 bf16 MFMA per wave,
// global_load_lds width=16 staging (LDS dest = wave-uniform base + lane*16).
__global__ __launch_bounds__(256, 3) void gemm_bt(const unsigned short* __restrict__ A,
                                                  const unsigned short* __restrict__ Bt,
                                                  float* __restrict__ C) {
  __shared__ alignas(16) unsigned short As[128 * 32];
  __shared__ alignas(16) unsigned short Bs[128 * 32];
  const int t    = threadIdx.x;
  const int wave = t >> 6;
  const int lane = t & 63;
  const int m0 = blockIdx.y * 128;
  const int n0 = blockIdx.x * 128;
  const int wm = (wave & 1) * 64;                  // wave's 64x64 subtile
  const int wn = (wave >> 1) * 64;
  const int lm = lane & 15;
  const int kg = lane >> 4;                        // k-group / row-quad

  f32x4 acc[4][4] = {};

  // staging: chunk c (16B) -> LDS row c>>2, col-chunk c&3 ; lane l of wave w = chunk base+l
  const int c0 = t, c1 = t + 256;
  const unsigned short* pa0 = A  + (size_t)(m0 + (c0 >> 2)) * K_DIM + (c0 & 3) * 8;
  const unsigned short* pa1 = A  + (size_t)(m0 + (c1 >> 2)) * K_DIM + (c1 & 3) * 8;
  const unsigned short* pb0 = Bt + (size_t)(n0 + (c0 >> 2)) * K_DIM + (c0 & 3) * 8;
  const unsigned short* pb1 = Bt + (size_t)(n0 + (c1 >> 2)) * K_DIM + (c1 & 3) * 8;
  unsigned short* lA0 = As + (wave * 64) * 8;      // wave-uniform LDS bases
  unsigned short* lA1 = As + (256 + wave * 64) * 8;
  unsigned short* lB0 = Bs + (wave * 64) * 8;
  unsigned short* lB1 = Bs + (256 + wave * 64) * 8;

  const int aoff = (wm + lm) * 32 + kg * 8;        // A fragment: row m, k = kg*8..+7
  const int boff = (wn + lm) * 32 + kg * 8;        // B fragment: row n, k = kg*8..+7

  for (int k0 = 0; k0 < K_DIM; k0 += 32) {
    __builtin_amdgcn_global_load_lds((const __attribute__((address_space(1))) unsigned int*)(pa0 + k0),
                                     (__attribute__((address_space(3))) unsigned int*)lA0, 16, 0, 0);
    __builtin_amdgcn_global_load_lds((const __attribute__((address_space(1))) unsigned int*)(pa1 + k0),
                                     (__attribute__((address_space(3))) unsigned int*)lA1, 16, 0, 0);
    __builtin_amdgcn_global_load_lds((const __attribute__((address_space(1))) unsigned int*)(pb0 + k0),
                                     (__attribute__((address_space(3))) unsigned int*)lB0, 16, 0, 0);
    __builtin_amdgcn_global_load_lds((const __attribute__((address_space(1))) unsigned int*)(pb1 + k0),
                                     (__attribute__((address_space(3))) unsigned int*)lB1, 16, 0, 0);
    __syncthreads();
    bf16x8 av[4], bv[4];
    #pragma unroll
    for (int mi = 0; mi < 4; ++mi)
      av[mi] = *(const bf16x8*)(As + aoff + mi * 16 * 32);
    #pragma unroll
    for (int ni = 0; ni < 4; ++ni)
      bv[ni] = *(const bf16x8*)(Bs + boff + ni * 16 * 32);
    #pragma unroll
    for (int mi = 0; mi < 4; ++mi) {
      #pragma unroll
      for (int ni = 0; ni < 4; ++ni)
        acc[mi][ni] = __builtin_amdgcn_mfma_f32_16x16x32_bf16(av[mi], bv[ni], acc[mi][ni], 0, 0, 0);
    }
    __syncthreads();
  }

  // C/D layout (m89/m91-verified): col = lane&15 (n), row = kg*4 + reg (m)
  #pragma unroll
  for (int mi = 0; mi < 4; ++mi) {
    #pragma unroll
    for (int ni = 0; ni < 4; ++ni) {
      float* p = C + (size_t)(m0 + wm + mi * 16 + kg * 4) * N_DIM + (n0 + wn + ni * 16 + lm);
      #pragma unroll
      for (int r = 0; r < 4; ++r)
        p[(size_t)r * N_DIM] = acc[mi][ni][r];
    }
  }
}

// ---------- kernel 4: gate epilogue ----------
__global__ void gate_epilogue(const float* __restrict__ C,
                              const float* __restrict__ bi, const float* __restrict__ bfv,
                              const float* __restrict__ bo, const float* __restrict__ bz,
                              const float* __restrict__ cprev, const float* __restrict__ nprev,
                              float* __restrict__ out) {
  int idx = blockIdx.x * 256 + threadIdx.x;        // 0..2,097,151 (float4 units)
  int b = idx >> 9;
  int j = (idx & 511) << 2;
  const float* base = C + (size_t)b * N_DIM + j;
  float4 pi = *(const float4*)(base);
  float4 pf = *(const float4*)(base + DH);
  float4 po = *(const float4*)(base + 2 * DH);
  float4 pz = *(const float4*)(base + 3 * DH);
  float4 vbi = *(const float4*)(bi + j);
  float4 vbf = *(const float4*)(bfv + j);
  float4 vbo = *(const float4*)(bo + j);
  float4 vbz = *(const float4*)(bz + j);
  size_t pidx = (((size_t)b) << 11) + j;
  float4 cp = *(const float4*)(cprev + pidx);
  float4 np = *(const float4*)(nprev + pidx);

  const float* Pi = (const float*)&pi; const float* Pf = (const float*)&pf;
  const float* Po = (const float*)&po; const float* Pz = (const float*)&pz;
  const float* Bi = (const float*)&vbi; const float* Bf = (const float*)&vbf;
  const float* Bo = (const float*)&vbo; const float* Bz = (const float*)&vbz;
  const float* Cp = (const float*)&cp; const float* Np = (const float*)&np;

  float rh[4], rc[4], rn[4];
  #pragma unroll
  for (int e = 0; e < 4; ++e) {
    float iv = __expf(Pi[e] + Bi[e]);
    float fv = __expf(Pf[e] + Bf[e]);
    float ao = Po[e] + Bo[e];
    float ov = 1.0f / (1.0f + __expf(-ao));
    float t2 = __expf(2.0f * (Pz[e] + Bz[e]));     // tanh = 1 - 2/(e^2x+1); inf-safe
    float zv = 1.0f - 2.0f / (t2 + 1.0f);
    float cv = fv * Cp[e] + iv * zv;
    float nv = fv * Np[e] + iv;
    rc[e] = cv; rn[e] = nv;
    rh[e] = ov * (cv / (nv + 1e-6f));
  }
  *(float4*)(out + pidx)            = make_float4(rh[0], rh[1], rh[2], rh[3]); // h
  *(float4*)(out + 8388608 + pidx)  = make_float4(rc[0], rc[1], rc[2], rc[3]); // c
  *(float4*)(out + 16777216 + pidx) = make_float4(rn[0], rn[1], rn[2], rn[3]); // n
}

extern "C" void kernel_launch(void* const* d_in, const int* in_sizes, int n_in,
                              void* d_out, int out_size, void* d_ws, size_t ws_size,
                              hipStream_t stream) {
  const float* x      = (const float*)d_in[0];
  const float* h_prev = (const float*)d_in[1];
  const float* c_prev = (const float*)d_in[2];
  const float* n_prev = (const float*)d_in[3];
  const float* W_i = (const float*)d_in[4];  const float* b_i = (const float*)d_in[5];  const float* U_i = (const float*)d_in[6];
  const float* W_f = (const float*)d_in[7];  const float* b_f = (const float*)d_in[8];  const float* U_f = (const float*)d_in[9];
  const float* W_o = (const float*)d_in[10]; const float* b_o = (const float*)d_in[11]; const float* U_o = (const float*)d_in[12];
  const float* W_z = (const float*)d_in[13]; const float* b_z = (const float*)d_in[14]; const float* U_z = (const float*)d_in[15];
  float* out = (float*)d_out;

  char* ws = (char*)d_ws;
  unsigned short* Abuf = (unsigned short*)ws;                           // 33,554,432 B
  unsigned short* Bt   = (unsigned short*)(ws + 33554432);              // 67,108,864 B
  float*          Cpre = (float*)(ws + 33554432 + 67108864);            // 134,217,728 B

  cast_cat_A<<<16384, 256, 0, stream>>>(x, h_prev, Abuf);
  transpose_cast_B<<<dim3(64, 128), 256, 0, stream>>>(W_i, U_i, W_f, U_f, W_o, U_o, W_z, U_z, Bt);
  gemm_bt<<<dim3(64, 32), 256, 0, stream>>>(Abuf, Bt, Cpre);
  gate_epilogue<<<8192, 256, 0, stream>>>(Cpre, b_i, b_f, b_o, b_z, c_prev, n_prev, out);
}

// Round 3
// 626.254 us; speedup vs baseline: 1.0377x; 1.0377x over previous
//
#include <hip/hip_runtime.h>
#include <hip/hip_bf16.h>
#include <stdint.h>

// Problem dims (fixed)
#define B_DIM 4096
#define DH    2048
#define K_DIM 4096   // D_IN + D_H (concat K)
#define N_DIM 8192   // 4 gates * DH (concat N), gate-interleaved layout (see n' mapping)

typedef __bf16  bf16x8 __attribute__((ext_vector_type(8)));
typedef float   f32x4  __attribute__((ext_vector_type(4)));

__device__ __forceinline__ unsigned short f2bf(float f) {
  // round-to-nearest-even bf16
  unsigned int u = __float_as_uint(f);
  u += 0x7FFFu + ((u >> 16) & 1u);
  return (unsigned short)(u >> 16);
}

// ---------- kernel 1: cast+concat x,h -> A bf16 [4096][4096] ----------
__global__ void cast_cat_A(const float* __restrict__ x, const float* __restrict__ h,
                           unsigned short* __restrict__ Abuf) {
  int idx = blockIdx.x * 256 + threadIdx.x;        // 0 .. 4,194,303
  const int half = B_DIM * (DH / 4);               // 2,097,152 float4 units per source
  bool isx = (idx < half);
  int i2 = isx ? idx : idx - half;
  int b  = i2 >> 9;                                // row
  int c4 = i2 & 511;                               // float4 col
  const float* src = (isx ? x : h) + (((size_t)b) << 11) + (c4 << 2);
  float4 v = *(const float4*)src;
  ushort4 o;
  o.x = f2bf(v.x); o.y = f2bf(v.y); o.z = f2bf(v.z); o.w = f2bf(v.w);
  int col = (isx ? 0 : DH) + (c4 << 2);
  *(ushort4*)(Abuf + (size_t)b * K_DIM + col) = o;
}

// ---------- kernel 2: transpose+cast weights -> Bt bf16 [8192][4096] ----------
// Gate-interleaved row layout so the GEMM epilogue gets all 4 gates per thread:
//   n'(g, j) = (j>>5)*128 + ((j&16)<<2) + g*16 + (j&15)
// Bt[n'][k]: k<2048 -> W_g[k][j], k>=2048 -> U_g[k-2048][j]
__global__ void transpose_cast_B(const float* __restrict__ Wi, const float* __restrict__ Ui,
                                 const float* __restrict__ Wf, const float* __restrict__ Uf,
                                 const float* __restrict__ Wo, const float* __restrict__ Uo,
                                 const float* __restrict__ Wz, const float* __restrict__ Uz,
                                 unsigned short* __restrict__ Bt) {
  __shared__ unsigned short lds[64 * 68];          // pad 68: 8B-aligned rows, broken bank stride
  const int k0 = blockIdx.x * 64;                  // 0..4032
  const int g  = blockIdx.y >> 5;                  // gate
  const int j0 = (blockIdx.y & 31) * 64;           // 0..1984
  const float* W = (g == 0) ? Wi : (g == 1) ? Wf : (g == 2) ? Wo : Wz;
  const float* U = (g == 0) ? Ui : (g == 1) ? Uf : (g == 2) ? Uo : Uz;
  const float* src = ((k0 < DH) ? (W + (size_t)k0 * DH)
                                : (U + (size_t)(k0 - DH) * DH)) + j0;
  const int t = threadIdx.x;
  #pragma unroll
  for (int r = 0; r < 4; ++r) {                    // read [k][j] coalesced along j
    int slot = r * 256 + t;                        // 1024 slots = 64 rows x 16 float4
    int kk = slot >> 4;
    int c4 = slot & 15;
    float4 v = *(const float4*)(src + (size_t)kk * DH + (c4 << 2));
    int n = c4 << 2;
    lds[(n + 0) * 68 + kk] = f2bf(v.x);
    lds[(n + 1) * 68 + kk] = f2bf(v.y);
    lds[(n + 2) * 68 + kk] = f2bf(v.z);
    lds[(n + 3) * 68 + kk] = f2bf(v.w);
  }
  __syncthreads();
  #pragma unroll
  for (int r = 0; r < 4; ++r) {                    // write [n'][k] coalesced along k
    int slot = r * 256 + t;
    int nn = slot >> 4;                            // local j offset 0..63
    int c8 = slot & 15;                            // 16 chunks of 4 shorts = 64 k
    int j  = j0 + nn;
    int np = ((j >> 5) << 7) + ((j & 16) << 2) + (g << 4) + (j & 15);
    *(ushort4*)(Bt + (size_t)np * K_DIM + k0 + (c8 << 2)) =
        *(const ushort4*)(lds + nn * 68 + (c8 << 2));
  }
}

// ---------- kernel 3: fused GEMM + gate epilogue ----------
// C_pre[4096][8192] = A @ Bt^T computed in-register; each thread's 4 ni-tiles are
// the 4 gates at the same (m, j) -> full sLSTM gate math in epilogue, no Cpre buffer.
__global__ __launch_bounds__(256, 3) void gemm_gates(const unsigned short* __restrict__ A,
                                                     const unsigned short* __restrict__ Bt,
                                                     const float* __restrict__ bi, const float* __restrict__ bf,
                                                     const float* __restrict__ bo, const float* __restrict__ bz,
                                                     const float* __restrict__ cprev, const float* __restrict__ nprev,
                                                     float* __restrict__ out) {
  __shared__ alignas(16) unsigned short As[128 * 32];
  __shared__ alignas(16) unsigned short Bs[128 * 32];
  const int t    = threadIdx.x;
  const int wave = t >> 6;
  const int lane = t & 63;
  const int m0 = blockIdx.y * 128;
  const int n0 = blockIdx.x * 128;                 // Bt row-tile base (gate-interleaved space)
  const int wm = (wave & 1) * 64;                  // wave's 64x64 subtile
  const int wn = (wave >> 1) * 64;
  const int lm = lane & 15;
  const int kg = lane >> 4;                        // k-group / row-quad

  f32x4 acc[4][4] = {};

  // staging: chunk c (16B) -> LDS row c>>2, col-chunk c&3 ; lane l of wave w = chunk base+l
  const int c0 = t, c1 = t + 256;
  const unsigned short* pa0 = A  + (size_t)(m0 + (c0 >> 2)) * K_DIM + (c0 & 3) * 8;
  const unsigned short* pa1 = A  + (size_t)(m0 + (c1 >> 2)) * K_DIM + (c1 & 3) * 8;
  const unsigned short* pb0 = Bt + (size_t)(n0 + (c0 >> 2)) * K_DIM + (c0 & 3) * 8;
  const unsigned short* pb1 = Bt + (size_t)(n0 + (c1 >> 2)) * K_DIM + (c1 & 3) * 8;
  unsigned short* lA0 = As + (wave * 64) * 8;      // wave-uniform LDS bases
  unsigned short* lA1 = As + (256 + wave * 64) * 8;
  unsigned short* lB0 = Bs + (wave * 64) * 8;
  unsigned short* lB1 = Bs + (256 + wave * 64) * 8;

  const int aoff = (wm + lm) * 32 + kg * 8;        // A fragment: row m, k = kg*8..+7
  const int boff = (wn + lm) * 32 + kg * 8;        // B fragment: row n', k = kg*8..+7

  for (int k0 = 0; k0 < K_DIM; k0 += 32) {
    __builtin_amdgcn_global_load_lds((const __attribute__((address_space(1))) unsigned int*)(pa0 + k0),
                                     (__attribute__((address_space(3))) unsigned int*)lA0, 16, 0, 0);
    __builtin_amdgcn_global_load_lds((const __attribute__((address_space(1))) unsigned int*)(pa1 + k0),
                                     (__attribute__((address_space(3))) unsigned int*)lA1, 16, 0, 0);
    __builtin_amdgcn_global_load_lds((const __attribute__((address_space(1))) unsigned int*)(pb0 + k0),
                                     (__attribute__((address_space(3))) unsigned int*)lB0, 16, 0, 0);
    __builtin_amdgcn_global_load_lds((const __attribute__((address_space(1))) unsigned int*)(pb1 + k0),
                                     (__attribute__((address_space(3))) unsigned int*)lB1, 16, 0, 0);
    __syncthreads();
    bf16x8 av[4], bv[4];
    #pragma unroll
    for (int mi = 0; mi < 4; ++mi)
      av[mi] = *(const bf16x8*)(As + aoff + mi * 16 * 32);
    #pragma unroll
    for (int ni = 0; ni < 4; ++ni)
      bv[ni] = *(const bf16x8*)(Bs + boff + ni * 16 * 32);
    #pragma unroll
    for (int mi = 0; mi < 4; ++mi) {
      #pragma unroll
      for (int ni = 0; ni < 4; ++ni)
        acc[mi][ni] = __builtin_amdgcn_mfma_f32_16x16x32_bf16(av[mi], bv[ni], acc[mi][ni], 0, 0, 0);
    }
    __syncthreads();
  }

  // Epilogue. Bt row r in tile: gate = (r>>4)&3 = ni for both wn halves;
  // j = blockIdx.x*32 + (wn?16:0) + lm. C/D layout: col=lane&15, row=kg*4+reg.
  const int jj = (blockIdx.x << 5) + ((wn >> 6) << 4) + lm;   // global j, 0..2047
  const float vbi = bi[jj], vbf = bf[jj], vbo = bo[jj], vbz = bz[jj];
  #pragma unroll
  for (int mi = 0; mi < 4; ++mi) {
    const int mrow = m0 + wm + mi * 16 + kg * 4;
    #pragma unroll
    for (int r = 0; r < 4; ++r) {
      const size_t idx = (size_t)(mrow + r) * DH + jj;
      float pi = acc[mi][0][r] + vbi;
      float pf = acc[mi][1][r] + vbf;
      float po = acc[mi][2][r] + vbo;
      float pz = acc[mi][3][r] + vbz;
      float iv = __expf(pi);
      float fv = __expf(pf);
      float ov = 1.0f / (1.0f + __expf(-po));
      float t2 = __expf(2.0f * pz);                // tanh = 1 - 2/(e^2x+1); inf-safe
      float zv = 1.0f - 2.0f / (t2 + 1.0f);
      float cv = fv * cprev[idx] + iv * zv;
      float nv = fv * nprev[idx] + iv;
      out[idx]            = ov * (cv / (nv + 1e-6f));  // h
      out[8388608 + idx]  = cv;                        // c
      out[16777216 + idx] = nv;                        // n
    }
  }
}

extern "C" void kernel_launch(void* const* d_in, const int* in_sizes, int n_in,
                              void* d_out, int out_size, void* d_ws, size_t ws_size,
                              hipStream_t stream) {
  const float* x      = (const float*)d_in[0];
  const float* h_prev = (const float*)d_in[1];
  const float* c_prev = (const float*)d_in[2];
  const float* n_prev = (const float*)d_in[3];
  const float* W_i = (const float*)d_in[4];  const float* b_i = (const float*)d_in[5];  const float* U_i = (const float*)d_in[6];
  const float* W_f = (const float*)d_in[7];  const float* b_f = (const float*)d_in[8];  const float* U_f = (const float*)d_in[9];
  const float* W_o = (const float*)d_in[10]; const float* b_o = (const float*)d_in[11]; const float* U_o = (const float*)d_in[12];
  const float* W_z = (const float*)d_in[13]; const float* b_z = (const float*)d_in[14]; const float* U_z = (const float*)d_in[15];
  float* out = (float*)d_out;

  char* ws = (char*)d_ws;
  unsigned short* Abuf = (unsigned short*)ws;                           // 33,554,432 B
  unsigned short* Bt   = (unsigned short*)(ws + 33554432);              // 67,108,864 B

  cast_cat_A<<<16384, 256, 0, stream>>>(x, h_prev, Abuf);
  transpose_cast_B<<<dim3(64, 128), 256, 0, stream>>>(W_i, U_i, W_f, U_f, W_o, U_o, W_z, U_z, Bt);
  gemm_gates<<<dim3(64, 32), 256, 0, stream>>>(Abuf, Bt, b_i, b_f, b_o, b_z, c_prev, n_prev, out);
}